// Round 1
// baseline (507.815 us; speedup 1.0000x reference)
//
#include <hip/hip_runtime.h>
#include <cmath>

// Problem constants (fixed by the reference; active_size == 512)
#define NB   32768
#define DIN  128
#define DMAX 1024
#define A    512

typedef _Float16 half8 __attribute__((ext_vector_type(8)));
typedef float f32x4 __attribute__((ext_vector_type(4)));

// ---------------- ws layout (in halves) ----------------
// [WS_RES_H, +262144)  Wres^T hi : 64 chunks (jb*16+kc) of 4096 = [128 j][32 k] (swizzled)
// [WS_RES_L, +262144)  Wres^T lo
// [WS_PAN + p*131072)  panel p (0=Win, 1..3=gates): 16 chunks (jb*4+kc) hi; lo at +65536
// [WS_X, +4194304)     X hi : 1024 chunks (mblk*4+kc) of [128 m][32 k] ; lo at +WS_X_LD
// [WS_P, +16777216)    P hi : 4096 chunks (mblk*16+kc)                 ; lo at +WS_P_LD
#define WS_RES_H 0
#define WS_RES_L 262144
#define WS_PAN   524288
#define WS_X     1048576
#define WS_X_LD  4194304
#define WS_P     9437184
#define WS_P_LD  16777216
#define WS_NEED_BYTES 85983232ull

// In-chunk XOR swizzle (8 KB chunks, 16B-granule preserving):
// byte b -> b ^ ((row&7)<<4) with row = b>>6. Spreads stride-64B row reads
// over all banks (2-way residual = free). Same map applied at store (prepass)
// and at ds_read (frag offsets); global_load_lds copies ws->LDS linearly.
#define SWZB(b) ((b) ^ ((((b) >> 6) & 7) << 4))
__device__ __forceinline__ unsigned swzh(unsigned h) { return h ^ (((h >> 5) & 7u) << 3); }

// ============================================================================
// FALLBACK PATH (ws too small): previous session's kernels, unchanged.
// ============================================================================
__global__ __launch_bounds__(256) void split_weights(
    const float* __restrict__ Wres, const float* __restrict__ Win,
    const float* __restrict__ Wg, _Float16* __restrict__ ws)
{
    int idx = blockIdx.x * 256 + threadIdx.x;  // 0 .. 524287
    if (idx < 262144) {
        int k = idx >> 9, j = idx & 511;
        float v = Wres[k * DMAX + j];
        _Float16 h = (_Float16)v;
        _Float16 l = (_Float16)(v - (float)h);
        int off = ((j >> 7) * 16 + (k >> 5)) * 4096 + (j & 127) * 32 + (k & 31);
        ws[WS_RES_H + off] = h;
        ws[WS_RES_L + off] = l;
    } else {
        int r = idx - 262144;
        int p = r >> 16;
        int q = r & 65535;
        int j = q >> 7, k = q & 127;
        float v = (p == 0) ? Win[j * DIN + k]
                           : Wg[((p - 1) * 512 + j) * DIN + k];
        _Float16 h = (_Float16)v;
        _Float16 l = (_Float16)(v - (float)h);
        int off = ((j >> 7) * 4 + (k >> 5)) * 4096 + (j & 127) * 32 + (k & 31);
        ws[WS_PAN + p * 131072 + off] = h;
        ws[WS_PAN + p * 131072 + 65536 + off] = l;
    }
}

__device__ __forceinline__ float sigm(float x) { return 1.0f / (1.0f + expf(-x)); }

__global__ __launch_bounds__(256, 2) void gser_mfma(
    const float* __restrict__ X, const float* __restrict__ P,
    const _Float16* __restrict__ ws,
    const float* __restrict__ lrp, const float* __restrict__ stp,
    float* __restrict__ out)
{
    __shared__ _Float16 Ah[128][40], Al[128][40], Bh[128][40], Bl[128][40];

    const int t    = threadIdx.x;
    const int lane = t & 63;
    const int w    = t >> 6;
    const int wm   = w & 1, wn = w >> 1;
    const int quad = lane >> 4, l16 = lane & 15;
    const int jb   = blockIdx.x;
    const int m0   = blockIdx.y * 128;
    const int j0   = jb * 128;

    const int sm = t >> 1;
    const int sk = (t & 1) * 16;

    auto stageA = [&](const float* src, int lda, int k0) {
        const float* p = src + (size_t)sm * lda + k0 + sk;
        float4 f0 = *(const float4*)(p);
        float4 f1 = *(const float4*)(p + 4);
        float4 f2 = *(const float4*)(p + 8);
        float4 f3 = *(const float4*)(p + 12);
        float fv[16] = {f0.x,f0.y,f0.z,f0.w, f1.x,f1.y,f1.z,f1.w,
                        f2.x,f2.y,f2.z,f2.w, f3.x,f3.y,f3.z,f3.w};
        half8 hh0, hh1, ll0, ll1;
#pragma unroll
        for (int i = 0; i < 8; ++i) {
            _Float16 h = (_Float16)fv[i];
            hh0[i] = h; ll0[i] = (_Float16)(fv[i] - (float)h);
        }
#pragma unroll
        for (int i = 0; i < 8; ++i) {
            _Float16 h = (_Float16)fv[8 + i];
            hh1[i] = h; ll1[i] = (_Float16)(fv[8 + i] - (float)h);
        }
        *(half8*)&Ah[sm][sk]     = hh0;
        *(half8*)&Ah[sm][sk + 8] = hh1;
        *(half8*)&Al[sm][sk]     = ll0;
        *(half8*)&Al[sm][sk + 8] = ll1;
    };

    auto stageB = [&](const _Float16* chH, const _Float16* chL) {
#pragma unroll
        for (int r = 0; r < 2; ++r) {
            int s  = t + r * 256;
            int bj = s >> 2, bk = (s & 3) * 8;
            *(half8*)&Bh[bj][bk] = *(const half8*)(chH + s * 8);
            *(half8*)&Bl[bj][bk] = *(const half8*)(chL + s * 8);
        }
    };

    auto mmac = [&](f32x4 (&C)[4][4]) {
        half8 fah[4], fal[4];
#pragma unroll
        for (int ms = 0; ms < 4; ++ms) {
            int row = wm * 64 + ms * 16 + l16;
            fah[ms] = *(const half8*)&Ah[row][quad * 8];
            fal[ms] = *(const half8*)&Al[row][quad * 8];
        }
#pragma unroll
        for (int js = 0; js < 4; ++js) {
            int col = wn * 64 + js * 16 + l16;
            half8 fbh = *(const half8*)&Bh[col][quad * 8];
            half8 fbl = *(const half8*)&Bl[col][quad * 8];
#pragma unroll
            for (int ms = 0; ms < 4; ++ms) {
                C[ms][js] = __builtin_amdgcn_mfma_f32_16x16x32_f16(fah[ms], fbh, C[ms][js], 0, 0, 0);
                C[ms][js] = __builtin_amdgcn_mfma_f32_16x16x32_f16(fah[ms], fbl, C[ms][js], 0, 0, 0);
                C[ms][js] = __builtin_amdgcn_mfma_f32_16x16x32_f16(fal[ms], fbh, C[ms][js], 0, 0, 0);
            }
        }
    };

    f32x4 accS[4][4];
#pragma unroll
    for (int i = 0; i < 4; ++i)
#pragma unroll
        for (int j = 0; j < 4; ++j)
            accS[i][j] = (f32x4){0.f, 0.f, 0.f, 0.f};

    const float* Pblk = P + (size_t)m0 * DMAX;
    for (int kc = 0; kc < 16; ++kc) {
        __syncthreads();
        stageA(Pblk, DMAX, kc * 32);
        const _Float16* ch = ws + WS_RES_H + (size_t)(jb * 16 + kc) * 4096;
        const _Float16* cl = ws + WS_RES_L + (size_t)(jb * 16 + kc) * 4096;
        stageB(ch, cl);
        __syncthreads();
        mmac(accS);
    }

    const float* Xblk = X + (size_t)m0 * DIN;
    for (int kc = 0; kc < 4; ++kc) {
        __syncthreads();
        stageA(Xblk, DIN, kc * 32);
        const _Float16* base = ws + WS_PAN + 0 * 131072;
        stageB(base + (size_t)(jb * 4 + kc) * 4096,
               base + 65536 + (size_t)(jb * 4 + kc) * 4096);
        __syncthreads();
        mmac(accS);
    }

    f32x4 accG[4][4];

#pragma unroll
    for (int i = 0; i < 4; ++i)
#pragma unroll
        for (int j = 0; j < 4; ++j)
            accG[i][j] = (f32x4){0.f, 0.f, 0.f, 0.f};
    for (int kc = 0; kc < 4; ++kc) {
        __syncthreads();
        stageA(Xblk, DIN, kc * 32);
        const _Float16* base = ws + WS_PAN + 1 * 131072;
        stageB(base + (size_t)(jb * 4 + kc) * 4096,
               base + 65536 + (size_t)(jb * 4 + kc) * 4096);
        __syncthreads();
        mmac(accG);
    }
#pragma unroll
    for (int ms = 0; ms < 4; ++ms)
#pragma unroll
        for (int js = 0; js < 4; ++js)
#pragma unroll
            for (int r = 0; r < 4; ++r)
                accS[ms][js][r] = tanhf(sigm(accG[ms][js][r]) * accS[ms][js][r]);

#pragma unroll
    for (int i = 0; i < 4; ++i)
#pragma unroll
        for (int j = 0; j < 4; ++j)
            accG[i][j] = (f32x4){0.f, 0.f, 0.f, 0.f};
    for (int kc = 0; kc < 4; ++kc) {
        __syncthreads();
        stageA(Xblk, DIN, kc * 32);
        const _Float16* base = ws + WS_PAN + 2 * 131072;
        stageB(base + (size_t)(jb * 4 + kc) * 4096,
               base + 65536 + (size_t)(jb * 4 + kc) * 4096);
        __syncthreads();
        mmac(accG);
    }
    {
        float lk[4];
#pragma unroll
        for (int js = 0; js < 4; ++js)
            lk[js] = sigm(lrp[j0 + wn * 64 + js * 16 + l16]);
#pragma unroll
        for (int ms = 0; ms < 4; ++ms)
#pragma unroll
            for (int r = 0; r < 4; ++r) {
                int row = m0 + wm * 64 + ms * 16 + quad * 4 + r;
#pragma unroll
                for (int js = 0; js < 4; ++js) {
                    int col = j0 + wn * 64 + js * 16 + l16;
                    float pv = P[(size_t)row * DMAX + col];
                    float fg = sigm(accG[ms][js][r]);
                    accS[ms][js][r] = (1.0f - lk[js]) * (fg * pv) + lk[js] * accS[ms][js][r];
                }
            }
    }

#pragma unroll
    for (int i = 0; i < 4; ++i)
#pragma unroll
        for (int j = 0; j < 4; ++j)
            accG[i][j] = (f32x4){0.f, 0.f, 0.f, 0.f};
    for (int kc = 0; kc < 4; ++kc) {
        __syncthreads();
        stageA(Xblk, DIN, kc * 32);
        const _Float16* base = ws + WS_PAN + 3 * 131072;
        stageB(base + (size_t)(jb * 4 + kc) * 4096,
               base + 65536 + (size_t)(jb * 4 + kc) * 4096);
        __syncthreads();
        mmac(accG);
    }
    {
        float thr[4];
#pragma unroll
        for (int js = 0; js < 4; ++js)
            thr[js] = log1pf(expf(stp[j0 + wn * 64 + js * 16 + l16]));
#pragma unroll
        for (int ms = 0; ms < 4; ++ms)
#pragma unroll
            for (int r = 0; r < 4; ++r) {
                int row = m0 + wm * 64 + ms * 16 + quad * 4 + r;
#pragma unroll
                for (int js = 0; js < 4; ++js) {
                    int col = j0 + wn * 64 + js * 16 + l16;
                    float st = sigm(accG[ms][js][r]) * accS[ms][js][r];
                    st = (st > thr[js]) ? (st - thr[js]) : st;
                    out[(size_t)row * DMAX + col] = st;
                }
            }
    }

#pragma unroll
    for (int i = 0; i < 16; ++i) {
        int s  = t + i * 256;
        int rr = s >> 5, c4 = s & 31;
        *(float4*)(out + (size_t)(m0 + rr) * DMAX + A + jb * 128 + c4 * 4) =
            (float4){0.f, 0.f, 0.f, 0.f};
    }
}

// ============================================================================
// MAIN PATH: full prepass split (W + X + P) into swizzled chunks, then a
// global_load_lds double-buffered MFMA kernel with zero staging VALU.
// ============================================================================

// Prepass: split all operands to fp16 hi/lo chunked panels in ws.
// Work granule = 8 consecutive k of one row -> one 16 B hi store + one lo
// store at the swizzled in-chunk offset (granule-preserving).
__global__ __launch_bounds__(256) void prep_full(
    const float* __restrict__ X, const float* __restrict__ P,
    const float* __restrict__ Wres, const float* __restrict__ Win,
    const float* __restrict__ Wg, _Float16* __restrict__ ws)
{
    const int NRES = 32768;                 // 512*512/8
    const int NPAN = 32768;                 // 4*512*128/8
    const int NX   = 524288;                // 32768*128/8
    const int NTOT = NRES + NPAN + NX + 2097152;  // + 32768*512/8
    for (int gi = blockIdx.x * 256 + threadIdx.x; gi < NTOT; gi += gridDim.x * 256) {
        float v[8];
        size_t dH, dL;
        if (gi < NRES) {
            int j = gi & 511, k0 = (gi >> 9) << 3;
#pragma unroll
            for (int i = 0; i < 8; ++i) v[i] = Wres[(size_t)(k0 + i) * DMAX + j];
            unsigned off = (unsigned)((j >> 7) * 16 + (k0 >> 5)) * 4096u
                         + swzh((unsigned)((j & 127) * 32 + (k0 & 31)));
            dH = WS_RES_H + off; dL = WS_RES_L + off;
        } else if (gi < NRES + NPAN) {
            int r = gi - NRES;
            int pj = r >> 4, k0 = (r & 15) << 3;
            int p = pj >> 9, j = pj & 511;
            const float* s = (p == 0) ? (Win + (size_t)j * DIN + k0)
                                      : (Wg + (size_t)((p - 1) * 512 + j) * DIN + k0);
            float4 f0 = *(const float4*)s, f1 = *(const float4*)(s + 4);
            v[0] = f0.x; v[1] = f0.y; v[2] = f0.z; v[3] = f0.w;
            v[4] = f1.x; v[5] = f1.y; v[6] = f1.z; v[7] = f1.w;
            unsigned off = (unsigned)((j >> 7) * 4 + (k0 >> 5)) * 4096u
                         + swzh((unsigned)((j & 127) * 32 + (k0 & 31)));
            dH = WS_PAN + (size_t)p * 131072 + off; dL = dH + 65536;
        } else if (gi < NRES + NPAN + NX) {
            int r = gi - (NRES + NPAN);
            int m = r >> 4, k0 = (r & 15) << 3;
            const float* s = X + (size_t)m * DIN + k0;
            float4 f0 = *(const float4*)s, f1 = *(const float4*)(s + 4);
            v[0] = f0.x; v[1] = f0.y; v[2] = f0.z; v[3] = f0.w;
            v[4] = f1.x; v[5] = f1.y; v[6] = f1.z; v[7] = f1.w;
            unsigned off = (unsigned)((m >> 7) * 4 + (k0 >> 5)) * 4096u
                         + swzh((unsigned)((m & 127) * 32 + (k0 & 31)));
            dH = WS_X + off; dL = dH + WS_X_LD;
        } else {
            int r = gi - (NRES + NPAN + NX);
            int m = r >> 6, k0 = (r & 63) << 3;
            const float* s = P + (size_t)m * DMAX + k0;
            float4 f0 = *(const float4*)s, f1 = *(const float4*)(s + 4);
            v[0] = f0.x; v[1] = f0.y; v[2] = f0.z; v[3] = f0.w;
            v[4] = f1.x; v[5] = f1.y; v[6] = f1.z; v[7] = f1.w;
            unsigned off = (unsigned)((m >> 7) * 16 + (k0 >> 5)) * 4096u
                         + swzh((unsigned)((m & 127) * 32 + (k0 & 31)));
            dH = WS_P + off; dL = dH + WS_P_LD;
        }
        half8 hh, ll;
#pragma unroll
        for (int i = 0; i < 8; ++i) {
            _Float16 h = (_Float16)v[i];
            hh[i] = h;
            ll[i] = (_Float16)(v[i] - (float)h);
        }
        *(half8*)(ws + dH) = hh;
        *(half8*)(ws + dL) = ll;
    }
}

__device__ __forceinline__ float fsigm(float x) { return 1.0f / (1.0f + __expf(-x)); }
__device__ __forceinline__ float ftanh(float x) {
    float e = __expf(-2.0f * fabsf(x));
    float t = (1.0f - e) / (1.0f + e);
    return (x < 0.0f) ? -t : t;
}

// async 16 B global -> LDS (dst must be wave-uniform; HW adds lane*16)
__device__ __forceinline__ void gl16(const _Float16* src, _Float16* dst) {
    __builtin_amdgcn_global_load_lds(
        (const __attribute__((address_space(1))) unsigned int*)src,
        (__attribute__((address_space(3))) unsigned int*)dst, 16, 0, 0);
}

__global__ __launch_bounds__(256, 2) void gser2(
    const float* __restrict__ X, const float* __restrict__ P,
    const _Float16* __restrict__ ws,
    const float* __restrict__ lrp, const float* __restrict__ stp,
    float* __restrict__ out)
{
    // [buf][ Ah 4096 | Al 4096 | Bh 4096 | Bl 4096 ] halves; 64 KB total
    __shared__ _Float16 lds[2][16384];

    const int t    = threadIdx.x;
    const int lane = t & 63;
    const int w    = t >> 6;
    const int wm   = w & 1, wn = w >> 1;
    const int quad = lane >> 4, l16 = lane & 15;

    // bijective XCD swizzle: the 4 jb-siblings of one m-panel land on the
    // same XCD (id%8) in consecutive rounds -> P chunks L2-hit.
    const int id = blockIdx.x;          // 0..1023
    const int x8 = id & 7;
    const int s8 = id >> 3;
    const int jb = s8 & 3;
    const int g  = (s8 >> 2) * 8 + x8;  // m-panel 0..255
    const int m0 = g * 128;
    const int j0 = jb * 128;

    // swizzled fragment byte offsets within an 8 KB chunk region
    int aOff[4], bOff[4];
#pragma unroll
    for (int ms = 0; ms < 4; ++ms) {
        int b = (wm * 64 + ms * 16 + l16) * 64 + quad * 16;
        aOff[ms] = SWZB(b);
    }
#pragma unroll
    for (int js = 0; js < 4; ++js) {
        int b = (wn * 64 + js * 16 + l16) * 64 + quad * 16;
        bOff[js] = SWZB(b);
    }

    const int so = w * 512 + lane * 8;  // per-lane src offset (halves)
    const int dd = w * 512;             // wave-uniform LDS dst offset (halves)

    // steps 0..15: A=P chunks, B=Wres; 16..31: A=X chunks, B=panel (s-16)>>2
    auto stage = [&](int buf, int s) {
        const _Float16 *aB, *bB;
        unsigned aLd, bLd;
        if (s < 16) {
            aB = ws + WS_P + (size_t)(g * 16 + s) * 4096;      aLd = WS_P_LD;
            bB = ws + WS_RES_H + (size_t)(jb * 16 + s) * 4096; bLd = 262144u;
        } else {
            int p = (s - 16) >> 2, kc = s & 3;
            aB = ws + WS_X + (size_t)(g * 4 + kc) * 4096;      aLd = WS_X_LD;
            bB = ws + WS_PAN + (size_t)p * 131072 + (size_t)(jb * 4 + kc) * 4096;
            bLd = 65536u;
        }
        _Float16* l = &lds[buf][0];
#pragma unroll
        for (int i = 0; i < 2; ++i) {
            gl16(aB + so + i * 2048,       l + dd + i * 2048);
            gl16(aB + aLd + so + i * 2048, l + 4096  + dd + i * 2048);
            gl16(bB + so + i * 2048,       l + 8192  + dd + i * 2048);
            gl16(bB + bLd + so + i * 2048, l + 12288 + dd + i * 2048);
        }
    };

    auto mmac = [&](int buf, f32x4 (&C)[4][4]) {
        const char* base = (const char*)&lds[buf][0];
        half8 fah[4], fal[4];
#pragma unroll
        for (int ms = 0; ms < 4; ++ms) {
            fah[ms] = *(const half8*)(base + aOff[ms]);
            fal[ms] = *(const half8*)(base + 8192 + aOff[ms]);
        }
#pragma unroll
        for (int js = 0; js < 4; ++js) {
            half8 fbh = *(const half8*)(base + 16384 + bOff[js]);
            half8 fbl = *(const half8*)(base + 24576 + bOff[js]);
#pragma unroll
            for (int ms = 0; ms < 4; ++ms) {
                C[ms][js] = __builtin_amdgcn_mfma_f32_16x16x32_f16(fah[ms], fbh, C[ms][js], 0, 0, 0);
                C[ms][js] = __builtin_amdgcn_mfma_f32_16x16x32_f16(fah[ms], fbl, C[ms][js], 0, 0, 0);
                C[ms][js] = __builtin_amdgcn_mfma_f32_16x16x32_f16(fal[ms], fbh, C[ms][js], 0, 0, 0);
            }
        }
    };

    f32x4 accS[4][4], accG[4][4];
#pragma unroll
    for (int i = 0; i < 4; ++i)
#pragma unroll
        for (int j = 0; j < 4; ++j)
            accS[i][j] = (f32x4){0.f, 0.f, 0.f, 0.f};

    int buf = 0;
    stage(0, 0);
    __syncthreads();

    // phase R: K=512 reservoir (steps 0..15) -> accS
    for (int s = 0; s < 16; ++s) {
        stage(buf ^ 1, s + 1);
        mmac(buf, accS);
        __syncthreads();
        buf ^= 1;
    }
    // W_in (steps 16..19) accumulates into accS
    for (int s = 16; s < 20; ++s) {
        stage(buf ^ 1, s + 1);
        mmac(buf, accS);
        __syncthreads();
        buf ^= 1;
    }

    // pass 1: i gate (steps 20..23)
#pragma unroll
    for (int i = 0; i < 4; ++i)
#pragma unroll
        for (int j = 0; j < 4; ++j)
            accG[i][j] = (f32x4){0.f, 0.f, 0.f, 0.f};
    for (int s = 20; s < 24; ++s) {
        stage(buf ^ 1, s + 1);
        mmac(buf, accG);
        __syncthreads();
        buf ^= 1;
    }
#pragma unroll
    for (int ms = 0; ms < 4; ++ms)
#pragma unroll
        for (int js = 0; js < 4; ++js)
#pragma unroll
            for (int r = 0; r < 4; ++r)
                accS[ms][js][r] = ftanh(fsigm(accG[ms][js][r]) * accS[ms][js][r]);

    // pass 2: f gate (steps 24..27)
#pragma unroll
    for (int i = 0; i < 4; ++i)
#pragma unroll
        for (int j = 0; j < 4; ++j)
            accG[i][j] = (f32x4){0.f, 0.f, 0.f, 0.f};
    for (int s = 24; s < 28; ++s) {
        stage(buf ^ 1, s + 1);
        mmac(buf, accG);
        __syncthreads();
        buf ^= 1;
    }
    {
        float lk[4];
#pragma unroll
        for (int js = 0; js < 4; ++js)
            lk[js] = fsigm(lrp[j0 + wn * 64 + js * 16 + l16]);
#pragma unroll
        for (int ms = 0; ms < 4; ++ms)
#pragma unroll
            for (int r = 0; r < 4; ++r) {
                int row = m0 + wm * 64 + ms * 16 + quad * 4 + r;
#pragma unroll
                for (int js = 0; js < 4; ++js) {
                    int col = j0 + wn * 64 + js * 16 + l16;
                    float pv = P[(size_t)row * DMAX + col];
                    float fg = fsigm(accG[ms][js][r]);
                    accS[ms][js][r] = (1.0f - lk[js]) * (fg * pv) + lk[js] * accS[ms][js][r];
                }
            }
    }

    // pass 3: o gate (steps 28..31)
#pragma unroll
    for (int i = 0; i < 4; ++i)
#pragma unroll
        for (int j = 0; j < 4; ++j)
            accG[i][j] = (f32x4){0.f, 0.f, 0.f, 0.f};
    for (int s = 28; s < 32; ++s) {
        if (s < 31) stage(buf ^ 1, s + 1);
        mmac(buf, accG);
        __syncthreads();
        buf ^= 1;
    }
    {
        float thr[4];
#pragma unroll
        for (int js = 0; js < 4; ++js)
            thr[js] = log1pf(__expf(stp[j0 + wn * 64 + js * 16 + l16]));
#pragma unroll
        for (int ms = 0; ms < 4; ++ms)
#pragma unroll
            for (int r = 0; r < 4; ++r) {
                int row = m0 + wm * 64 + ms * 16 + quad * 4 + r;
#pragma unroll
                for (int js = 0; js < 4; ++js) {
                    int col = j0 + wn * 64 + js * 16 + l16;
                    float st = fsigm(accG[ms][js][r]) * accS[ms][js][r];
                    st = (st > thr[js]) ? (st - thr[js]) : st;
                    out[(size_t)row * DMAX + col] = st;
                }
            }
    }

    // zero-pad cols [512,1024): this block covers [512 + jb*128, +128)
#pragma unroll
    for (int i = 0; i < 16; ++i) {
        int s  = t + i * 256;
        int rr = s >> 5, c4 = s & 31;
        *(float4*)(out + (size_t)(m0 + rr) * DMAX + A + jb * 128 + c4 * 4) =
            (float4){0.f, 0.f, 0.f, 0.f};
    }
}

extern "C" void kernel_launch(void* const* d_in, const int* in_sizes, int n_in,
                              void* d_out, int out_size, void* d_ws, size_t ws_size,
                              hipStream_t stream) {
    const float* X    = (const float*)d_in[0];
    const float* P    = (const float*)d_in[1];
    const float* Wres = (const float*)d_in[2];
    const float* Win  = (const float*)d_in[3];
    const float* Wg   = (const float*)d_in[4];
    const float* lrp  = (const float*)d_in[5];
    const float* stp  = (const float*)d_in[6];
    float* out = (float*)d_out;
    _Float16* ws = (_Float16*)d_ws;

    if (ws_size >= WS_NEED_BYTES) {
        hipLaunchKernelGGL(prep_full, dim3(10496), dim3(256), 0, stream,
                           X, P, Wres, Win, Wg, ws);
        hipLaunchKernelGGL(gser2, dim3(1024), dim3(256), 0, stream,
                           X, P, ws, lrp, stp, out);
    } else {
        hipLaunchKernelGGL(split_weights, dim3(2048), dim3(256), 0, stream,
                           Wres, Win, Wg, ws);
        hipLaunchKernelGGL(gser_mfma, dim3(4, 256), dim3(256), 0, stream,
                           X, P, ws, lrp, stp, out);
    }
}

// Round 2
// 498.521 us; speedup vs baseline: 1.0186x; 1.0186x over previous
//
#include <hip/hip_runtime.h>
#include <cmath>

// Problem constants (fixed by the reference; active_size == 512)
#define NB   32768
#define DIN  128
#define DMAX 1024
#define A    512

typedef _Float16 half8 __attribute__((ext_vector_type(8)));
typedef float f32x4 __attribute__((ext_vector_type(4)));

// ---------------- ws layout (halves; 2 MB total) ----------------
// [WS_RES_H, +262144) : Wres^T hi, 64 chunks (jb*16+kc) of 4096 h = [128 j][32 k], swizzled
// [WS_RES_L, +262144) : Wres^T lo, same
// [WS_PAN + p*131072) : panel p (0=Win, 1..3 = i/f/o gate): 16 chunks (jb*4+kc) hi; lo at +65536
#define WS_RES_H 0
#define WS_RES_L 262144
#define WS_PAN   524288

// In-chunk XOR swizzle (verified store/read pair from the previous passing
// kernel): byte b -> b ^ (((b>>6)&7)<<4). Applied at ws store (prep) and at
// LDS ds_write/ds_read; global_load_lds copies ws->LDS linearly in between.
#define SWZB(b) ((b) ^ ((((b) >> 6) & 7) << 4))
__device__ __forceinline__ unsigned swzh(unsigned h) { return h ^ (((h >> 5) & 7u) << 3); }

__device__ __forceinline__ float fsigm(float x) { return 1.0f / (1.0f + __expf(-x)); }
__device__ __forceinline__ float ftanh(float x) {
    float e = __expf(-2.0f * fabsf(x));
    float t = (1.0f - e) / (1.0f + e);
    return (x < 0.0f) ? -t : t;
}

// async 16 B global -> LDS (LDS dst wave-uniform; HW adds lane*16)
__device__ __forceinline__ void gl16(const _Float16* src, _Float16* dst) {
    __builtin_amdgcn_global_load_lds(
        (const __attribute__((address_space(1))) unsigned int*)src,
        (__attribute__((address_space(3))) unsigned int*)dst, 16, 0, 0);
}

// ============================================================================
// Prepass: transpose + fp16 hi/lo split of the WEIGHTS ONLY into ws (2 MB),
// chunked [128 j][32 k], pre-swizzled so linear DMA into LDS lands swizzled.
// One thread = one (chunk, j) pair -> 32 strided/contig loads, 8x16B stores.
// ============================================================================
__global__ __launch_bounds__(256) void prep_w(
    const float* __restrict__ Wres, const float* __restrict__ Win,
    const float* __restrict__ Wg, _Float16* __restrict__ ws)
{
    int tid = blockIdx.x * 256 + threadIdx.x;   // 0 .. 16383
    float v[32];
    size_t dH, dL;
    int j = tid & 127;
    if (tid < 8192) {
        // Wres^T: chunk c = jbb*16+kc covers cols jbb*128+j, rows kc*32..+32
        int c = tid >> 7;
        int jbb = c >> 4, kc = c & 15;
        int col = jbb * 128 + j;
#pragma unroll
        for (int i = 0; i < 32; ++i)
            v[i] = Wres[(size_t)(kc * 32 + i) * DMAX + col];
        dH = WS_RES_H + (size_t)c * 4096;
        dL = WS_RES_L + (size_t)c * 4096;
    } else {
        // panels: c = p*16 + jbb*4 + kc; row jbb*128+j, k = kc*32..+32
        int r = tid - 8192;
        int c = r >> 7;
        int p = c >> 4, cc = c & 15;
        int jbb = cc >> 2, kc = cc & 3;
        int row = jbb * 128 + j;
        const float* s = (p == 0) ? (Win + (size_t)row * DIN + kc * 32)
                                  : (Wg + (size_t)((p - 1) * 512 + row) * DIN + kc * 32);
#pragma unroll
        for (int i = 0; i < 32; ++i) v[i] = s[i];
        dH = WS_PAN + (size_t)p * 131072 + (size_t)(jbb * 4 + kc) * 4096;
        dL = dH + 65536;
    }
#pragma unroll
    for (int g = 0; g < 4; ++g) {
        half8 hh, ll;
#pragma unroll
        for (int i = 0; i < 8; ++i) {
            float x = v[g * 8 + i];
            _Float16 h = (_Float16)x;
            hh[i] = h;
            ll[i] = (_Float16)(x - (float)h);
        }
        unsigned ho = swzh((unsigned)(j * 32 + g * 8));
        *(half8*)(ws + dH + ho) = hh;
        *(half8*)(ws + dL + ho) = ll;
    }
}

// ============================================================================
// Fused kernel. Block = 128m x 128j, 4 waves 2x2, wave 64x64 as 4x4 of
// mfma_f32_16x16x32_f16; split-fp16 3-product accumulation (fp32-equivalent).
// Per K-step (BK=32): issue A(s+1) fp32->VGPR + B(s+1) ws->LDS DMA, then
// mmac(s) hides the latency, then convert+ds_write A(s+1), one barrier.
// LDS double buffer: [buf][Ah 8KB | Al 8KB | Bh 8KB | Bl 8KB] = 64 KB.
// ============================================================================
__global__ __launch_bounds__(256, 2) void gser3(
    const float* __restrict__ X,    // [NB, DIN]
    const float* __restrict__ P,    // [NB, DMAX]
    const _Float16* __restrict__ ws,
    const float* __restrict__ lrp, const float* __restrict__ stp,
    float* __restrict__ out)        // [NB, DMAX]
{
    __shared__ _Float16 lds[2][16384] __attribute__((aligned(16)));

    const int t    = threadIdx.x;
    const int lane = t & 63;
    const int w    = t >> 6;
    const int wm   = w & 1, wn = w >> 1;
    const int quad = lane >> 4, l16 = lane & 15;

    // XCD-grouped decode: the 4 jb-siblings of one m-panel land on one XCD
    // within 32 consecutive ids -> shared P rows hit that XCD's L2/L3.
    const int id = blockIdx.x;          // 0..1023
    const int x8 = id & 7;
    const int s8 = id >> 3;
    const int jb = s8 & 3;
    const int g  = (s8 >> 2) * 8 + x8;  // m-panel 0..255
    const int m0 = g * 128;
    const int j0 = jb * 128;

    const float* Pblk = P + (size_t)m0 * DMAX;
    const float* Xblk = X + (size_t)m0 * DIN;

    // swizzled fragment byte offsets within an 8 KB region
    int aOff[4], bOff[4];
#pragma unroll
    for (int ms = 0; ms < 4; ++ms) {
        int b = (wm * 64 + ms * 16 + l16) * 64 + quad * 16;
        aOff[ms] = SWZB(b);
    }
#pragma unroll
    for (int js = 0; js < 4; ++js) {
        int b = (wn * 64 + js * 16 + l16) * 64 + quad * 16;
        bOff[js] = SWZB(b);
    }

    // A staging: thread -> (row sm, k-offset sk), 16 floats = 64 B
    const int sm = t >> 1;
    const int sk = (t & 1) * 16;

    // B DMA: wave w covers halves [w*1024, +1024) of each 4096-half region
    auto stageB = [&](int buf, int s) {
        const _Float16 *chH, *chL;
        if (s < 16) {
            chH = ws + WS_RES_H + (size_t)(jb * 16 + s) * 4096;
            chL = ws + WS_RES_L + (size_t)(jb * 16 + s) * 4096;
        } else {
            int p = (s - 16) >> 2, kc = s & 3;
            chH = ws + WS_PAN + (size_t)p * 131072 + (size_t)(jb * 4 + kc) * 4096;
            chL = chH + 65536;
        }
        _Float16* l = &lds[buf][0];
        gl16(chH + w * 1024 + lane * 8,       l + 8192  + w * 1024);
        gl16(chH + w * 1024 + 512 + lane * 8, l + 8192  + w * 1024 + 512);
        gl16(chL + w * 1024 + lane * 8,       l + 12288 + w * 1024);
        gl16(chL + w * 1024 + 512 + lane * 8, l + 12288 + w * 1024 + 512);
    };

    // convert 16 fp32 -> hi/lo half8 pairs, swizzled ds_write
    auto writeA = [&](int buf, float4 r0, float4 r1, float4 r2, float4 r3) {
        float fv[16] = {r0.x,r0.y,r0.z,r0.w, r1.x,r1.y,r1.z,r1.w,
                        r2.x,r2.y,r2.z,r2.w, r3.x,r3.y,r3.z,r3.w};
        half8 h0, h1, l0, l1;
#pragma unroll
        for (int i = 0; i < 8; ++i) {
            _Float16 h = (_Float16)fv[i];
            h0[i] = h; l0[i] = (_Float16)(fv[i] - (float)h);
        }
#pragma unroll
        for (int i = 0; i < 8; ++i) {
            _Float16 h = (_Float16)fv[8 + i];
            h1[i] = h; l1[i] = (_Float16)(fv[8 + i] - (float)h);
        }
        char* base = (char*)&lds[buf][0];
        int a0 = SWZB(sm * 64 + sk * 2);
        int a1 = SWZB(sm * 64 + sk * 2 + 16);
        *(half8*)(base + a0) = h0;
        *(half8*)(base + a1) = h1;
        *(half8*)(base + 8192 + a0) = l0;
        *(half8*)(base + 8192 + a1) = l1;
    };

    auto mmac = [&](int buf, f32x4 (&C)[4][4]) {
        const char* base = (const char*)&lds[buf][0];
        half8 fah[4], fal[4];
#pragma unroll
        for (int ms = 0; ms < 4; ++ms) {
            fah[ms] = *(const half8*)(base + aOff[ms]);
            fal[ms] = *(const half8*)(base + 8192 + aOff[ms]);
        }
#pragma unroll
        for (int js = 0; js < 4; ++js) {
            half8 fbh = *(const half8*)(base + 16384 + bOff[js]);
            half8 fbl = *(const half8*)(base + 24576 + bOff[js]);
#pragma unroll
            for (int ms = 0; ms < 4; ++ms) {
                C[ms][js] = __builtin_amdgcn_mfma_f32_16x16x32_f16(fah[ms], fbh, C[ms][js], 0, 0, 0);
                C[ms][js] = __builtin_amdgcn_mfma_f32_16x16x32_f16(fah[ms], fbl, C[ms][js], 0, 0, 0);
                C[ms][js] = __builtin_amdgcn_mfma_f32_16x16x32_f16(fal[ms], fbh, C[ms][js], 0, 0, 0);
            }
        }
    };

    // one pipelined K-step: issue A(s+1)+B(s+1), mmac(s), write A(s+1), barrier
    auto krnstep = [&](int s, f32x4 (&acc)[4][4], bool last) {
        const int bcur = s & 1, bnxt = bcur ^ 1;
        float4 r0, r1, r2, r3;
        if (!last) {
            const int sn = s + 1;
            const float* srcA = (sn < 16)
                ? (Pblk + (size_t)sm * DMAX + sn * 32 + sk)
                : (Xblk + (size_t)sm * DIN + (sn & 3) * 32 + sk);
            r0 = *(const float4*)(srcA);
            r1 = *(const float4*)(srcA + 4);
            r2 = *(const float4*)(srcA + 8);
            r3 = *(const float4*)(srcA + 12);
            stageB(bnxt, sn);
        }
        mmac(bcur, acc);
        if (!last) writeA(bnxt, r0, r1, r2, r3);
        __syncthreads();
    };

    f32x4 accS[4][4], accG[4][4];
#pragma unroll
    for (int i = 0; i < 4; ++i)
#pragma unroll
        for (int j = 0; j < 4; ++j)
            accS[i][j] = (f32x4){0.f, 0.f, 0.f, 0.f};

    // prologue: fill buf0 with A(0), B(0)
    {
        const float* srcA = Pblk + (size_t)sm * DMAX + sk;
        float4 r0 = *(const float4*)(srcA);
        float4 r1 = *(const float4*)(srcA + 4);
        float4 r2 = *(const float4*)(srcA + 8);
        float4 r3 = *(const float4*)(srcA + 12);
        stageB(0, 0);
        writeA(0, r0, r1, r2, r3);
        __syncthreads();
    }

    // phase R (K=512, steps 0..15) + W_in (16..19) -> accS
    for (int s = 0; s < 20; ++s) krnstep(s, accS, false);

    // pass 1: i gate (20..23); accS = tanh(sigm(g)*accS)
#pragma unroll
    for (int i = 0; i < 4; ++i)
#pragma unroll
        for (int j = 0; j < 4; ++j)
            accG[i][j] = (f32x4){0.f, 0.f, 0.f, 0.f};
    for (int s = 20; s < 24; ++s) krnstep(s, accG, false);
#pragma unroll
    for (int ms = 0; ms < 4; ++ms)
#pragma unroll
        for (int js = 0; js < 4; ++js)
#pragma unroll
            for (int r = 0; r < 4; ++r)
                accS[ms][js][r] = ftanh(fsigm(accG[ms][js][r]) * accS[ms][js][r]);

    // pass 2: f gate (24..27); accS = (1-leak)*(fg*prev) + leak*accS
#pragma unroll
    for (int i = 0; i < 4; ++i)
#pragma unroll
        for (int j = 0; j < 4; ++j)
            accG[i][j] = (f32x4){0.f, 0.f, 0.f, 0.f};
    for (int s = 24; s < 28; ++s) krnstep(s, accG, false);
    {
        float lk[4];
#pragma unroll
        for (int js = 0; js < 4; ++js)
            lk[js] = fsigm(lrp[j0 + wn * 64 + js * 16 + l16]);
#pragma unroll
        for (int ms = 0; ms < 4; ++ms)
#pragma unroll
            for (int r = 0; r < 4; ++r) {
                int row = m0 + wm * 64 + ms * 16 + quad * 4 + r;
#pragma unroll
                for (int js = 0; js < 4; ++js) {
                    int col = j0 + wn * 64 + js * 16 + l16;
                    float pv = P[(size_t)row * DMAX + col];
                    float fg = fsigm(accG[ms][js][r]);
                    accS[ms][js][r] = (1.0f - lk[js]) * (fg * pv) + lk[js] * accS[ms][js][r];
                }
            }
    }

    // pass 3: o gate (28..31); st = sigm(g)*accS; spike threshold; store
#pragma unroll
    for (int i = 0; i < 4; ++i)
#pragma unroll
        for (int j = 0; j < 4; ++j)
            accG[i][j] = (f32x4){0.f, 0.f, 0.f, 0.f};
    for (int s = 28; s < 31; ++s) krnstep(s, accG, false);
    krnstep(31, accG, true);
    {
        float thr[4];
#pragma unroll
        for (int js = 0; js < 4; ++js)
            thr[js] = log1pf(__expf(stp[j0 + wn * 64 + js * 16 + l16]));
#pragma unroll
        for (int ms = 0; ms < 4; ++ms)
#pragma unroll
            for (int r = 0; r < 4; ++r) {
                int row = m0 + wm * 64 + ms * 16 + quad * 4 + r;
#pragma unroll
                for (int js = 0; js < 4; ++js) {
                    int col = j0 + wn * 64 + js * 16 + l16;
                    float st = fsigm(accG[ms][js][r]) * accS[ms][js][r];
                    st = (st > thr[js]) ? (st - thr[js]) : st;
                    out[(size_t)row * DMAX + col] = st;
                }
            }
    }

    // zero-pad cols [512,1024): this block covers [512 + jb*128, +128)
#pragma unroll
    for (int i = 0; i < 16; ++i) {
        int s  = t + i * 256;
        int rr = s >> 5, c4 = s & 31;
        *(float4*)(out + (size_t)(m0 + rr) * DMAX + A + jb * 128 + c4 * 4) =
            (float4){0.f, 0.f, 0.f, 0.f};
    }
}

extern "C" void kernel_launch(void* const* d_in, const int* in_sizes, int n_in,
                              void* d_out, int out_size, void* d_ws, size_t ws_size,
                              hipStream_t stream) {
    const float* X    = (const float*)d_in[0];
    const float* P    = (const float*)d_in[1];
    const float* Wres = (const float*)d_in[2];
    const float* Win  = (const float*)d_in[3];
    const float* Wg   = (const float*)d_in[4];
    const float* lrp  = (const float*)d_in[5];
    const float* stp  = (const float*)d_in[6];
    float* out = (float*)d_out;
    _Float16* ws = (_Float16*)d_ws;   // uses 2 MB

    hipLaunchKernelGGL(prep_w, dim3(64), dim3(256), 0, stream,
                       Wres, Win, Wg, ws);
    hipLaunchKernelGGL(gser3, dim3(1024), dim3(256), 0, stream,
                       X, P, ws, lrp, stp, out);
}